// Round 11
// baseline (935.524 us; speedup 1.0000x reference)
//
#include <hip/hip_runtime.h>
#include <hip/hip_bf16.h>
#include <stdint.h>

#define O_N 100000
#define T_N 400000
#define NCH1 1563   // ceil(400000/256)
#define NCH3 391    // ceil(100000/256)
#define NCHW 25000  // 400000/16 wave-chunks for gemm1
#define PBLKS 512
#define HBLKS 512

typedef __attribute__((ext_vector_type(8))) short short8;
typedef __attribute__((ext_vector_type(4))) float f32x4;
typedef __attribute__((ext_vector_type(16))) float f32x16;
typedef unsigned short ushort_t;

__device__ __forceinline__ unsigned short f2bf(float x) {
    union { float f; unsigned u; } v; v.f = x;
    unsigned u = v.u;
    unsigned rounded = u + 0x7FFF + ((u >> 16) & 1);
    return (unsigned short)(rounded >> 16);
}

__device__ __forceinline__ short8 pack8(f32x4 a, f32x4 b) {
    short8 t;
    t[0] = (short)f2bf(a[0]); t[1] = (short)f2bf(a[1]);
    t[2] = (short)f2bf(a[2]); t[3] = (short)f2bf(a[3]);
    t[4] = (short)f2bf(b[0]); t[5] = (short)f2bf(b[1]);
    t[6] = (short)f2bf(b[2]); t[7] = (short)f2bf(b[3]);
    return t;
}

// B-fragment pack for mfma_f32_32x32x16_bf16
__global__ void pack_b32(const float* __restrict__ W, ushort_t* __restrict__ out,
                         int Ksteps, int NT, int ldw, int col0) {
    int idx = blockIdx.x * 256 + threadIdx.x;
    int total = Ksteps * NT * 512;
    if (idx >= total) return;
    int j = idx & 7;
    int lane = (idx >> 3) & 63;
    int t2 = idx >> 9;
    int nt = t2 % NT;
    int ks = t2 / NT;
    int k = ks * 16 + ((lane >> 5) << 3) + j;
    int n = col0 + (nt << 5) + (lane & 31);
    out[idx] = f2bf(W[(size_t)k * ldw + n]);
}

// B-fragment pack for mfma_f32_16x16x32_bf16 (gemm1 + fallback)
__global__ void pack_b(const float* __restrict__ W, unsigned short* __restrict__ out,
                       int K, int Ntiles, int ldw, int col0) {
    int idx = blockIdx.x * 256 + threadIdx.x;
    int total = K * Ntiles * 16;
    if (idx >= total) return;
    int j = idx & 7;
    int lane = (idx >> 3) & 63;
    int t2 = idx >> 9;
    int ntile = t2 % Ntiles;
    int kstep = t2 / Ntiles;
    int k = kstep * 32 + ((lane >> 4) << 3) + j;
    int n = (ntile << 4) + (lane & 15);
    out[idx] = f2bf(W[(size_t)k * ldw + col0 + n]);
}

// pack [W1b_s ; W1b_o] (K=256) for pooled_k
__global__ void pack_bso(const float* __restrict__ W1b, ushort_t* __restrict__ out) {
    int idx = blockIdx.x * 256 + threadIdx.x;
    if (idx >= 32768) return;
    int j = idx & 7;
    int lane = (idx >> 3) & 63;
    int t2 = idx >> 9;
    int nt = t2 & 3;
    int ks = t2 >> 2;
    int k = ks * 16 + ((lane >> 5) << 3) + j;
    int n = (nt << 5) + (lane & 31);
    float v = (k < 128) ? W1b[(size_t)k * 384 + n] : W1b[(size_t)(k - 128) * 384 + 256 + n];
    out[idx] = f2bf(v);
}

// per-side segment counts
__global__ void counts2_k(const int* __restrict__ edges,
                          float* __restrict__ cs, float* __restrict__ co) {
    int idx = blockIdx.x * 256 + threadIdx.x;
    if (idx >= T_N) return;
    int2 e = ((const int2*)edges)[idx];
    atomicAdd(&cs[e.x], 1.0f);
    atomicAdd(&co[e.y], 1.0f);
}

// exclusive scan of two count arrays (block 0: cs, block 1: co); writes off + cursor copy
__global__ __launch_bounds__(1024) void scan_k(
    const float* __restrict__ c0, int* __restrict__ off0, int* __restrict__ cur0,
    const float* __restrict__ c1, int* __restrict__ off1, int* __restrict__ cur1)
{
    const float* cnt = blockIdx.x ? c1 : c0;
    int* off = blockIdx.x ? off1 : off0;
    int* cur = blockIdx.x ? cur1 : cur0;
    __shared__ int part[1024];
    int tid = threadIdx.x;
    const int chunk = 98;           // 1024*98 >= 100000
    int s0 = tid * chunk;
    int e0 = s0 + chunk; if (e0 > O_N) e0 = O_N; if (s0 > O_N) s0 = O_N;
    int s = 0;
    for (int i = s0; i < e0; ++i) s += (int)cnt[i];
    part[tid] = s;
    __syncthreads();
    for (int d = 1; d < 1024; d <<= 1) {
        int v = (tid >= d) ? part[tid - d] : 0;
        __syncthreads();
        part[tid] += v;
        __syncthreads();
    }
    int base = part[tid] - s;
    for (int i = s0; i < e0; ++i) {
        int c = (int)cnt[i];
        off[i] = base; cur[i] = base;
        base += c;
    }
    if (tid == 1023) off[O_N] = part[1023];
}

// bucket-scatter triple ids into CSR lists
__global__ void scatter_k(const int* __restrict__ edges,
                          int* __restrict__ scur, int* __restrict__ ocur,
                          int* __restrict__ slist, int* __restrict__ olist) {
    int idx = blockIdx.x * 256 + threadIdx.x;
    if (idx >= T_N) return;
    int2 e = ((const int2*)edges)[idx];
    int ps = atomicAdd(&scur[e.x], 1);
    slist[ps] = idx;
    int po = atomicAdd(&ocur[e.y], 1);
    olist[po] = idx;
}

// K1 (round 7, proven): 16 waves/block, zero steady-state barriers.
__global__ __launch_bounds__(1024, 4) void gemm1_k(
    const float* __restrict__ obj_vecs, const float* __restrict__ pred_vecs,
    const int* __restrict__ edges,
    const ushort_t* __restrict__ W1a_p, const float* __restrict__ b1a,
    ushort_t* __restrict__ hbuf)
{
    __shared__ __align__(16) ushort_t Wl[49152];
    __shared__ __align__(16) ushort_t hx[16][1088];
    const int tid = threadIdx.x;
    const int l = tid & 63;
    const int w = tid >> 6;
    const int r16 = l & 15;
    const int kq = l >> 4;

    {
        const short8* s = reinterpret_cast<const short8*>(W1a_p);
        short8* d = reinterpret_cast<short8*>(Wl);
        #pragma unroll
        for (int i = 0; i < 6; ++i) d[i * 1024 + tid] = s[i * 1024 + tid];
    }
    __syncthreads();

    float bias[8];
    #pragma unroll
    for (int nt = 0; nt < 8; ++nt) bias[nt] = b1a[nt * 16 + r16];

    ushort_t* hw = hx[w];
    const int2* e2 = (const int2*)edges;
    const int stride = gridDim.x * 16;

    for (int ch = blockIdx.x * 16 + w; ch < NCHW; ch += stride) {
        int tri = ch * 16 + r16;
        int2 e = e2[tri];
        const float* ps = obj_vecs  + (size_t)e.x * 128;
        const float* pp = pred_vecs + (size_t)tri * 128;
        const float* po = obj_vecs  + (size_t)e.y * 128;

        f32x4 acc[8];
        #pragma unroll
        for (int nt = 0; nt < 8; ++nt) acc[nt] = (f32x4){0.f, 0.f, 0.f, 0.f};

        {
            short8 af[4];
            #pragma unroll
            for (int ks = 0; ks < 4; ++ks) {
                f32x4 v0 = *reinterpret_cast<const f32x4*>(ps + ks * 32 + kq * 8);
                f32x4 v1 = *reinterpret_cast<const f32x4*>(ps + ks * 32 + kq * 8 + 4);
                af[ks] = pack8(v0, v1);
            }
            #pragma unroll
            for (int ks = 0; ks < 4; ++ks)
                #pragma unroll
                for (int nt = 0; nt < 8; ++nt) {
                    short8 b = *reinterpret_cast<const short8*>(&Wl[((ks * 8 + nt) * 64 + l) * 8]);
                    acc[nt] = __builtin_amdgcn_mfma_f32_16x16x32_bf16(af[ks], b, acc[nt], 0, 0, 0);
                }
        }
        {
            short8 af[4];
            #pragma unroll
            for (int ks = 0; ks < 4; ++ks) {
                f32x4 v0 = *reinterpret_cast<const f32x4*>(pp + ks * 32 + kq * 8);
                f32x4 v1 = *reinterpret_cast<const f32x4*>(pp + ks * 32 + kq * 8 + 4);
                af[ks] = pack8(v0, v1);
            }
            #pragma unroll
            for (int ks = 0; ks < 4; ++ks)
                #pragma unroll
                for (int nt = 0; nt < 8; ++nt) {
                    short8 b = *reinterpret_cast<const short8*>(&Wl[(((ks + 4) * 8 + nt) * 64 + l) * 8]);
                    acc[nt] = __builtin_amdgcn_mfma_f32_16x16x32_bf16(af[ks], b, acc[nt], 0, 0, 0);
                }
        }
        {
            short8 af[4];
            #pragma unroll
            for (int ks = 0; ks < 4; ++ks) {
                f32x4 v0 = *reinterpret_cast<const f32x4*>(po + ks * 32 + kq * 8);
                f32x4 v1 = *reinterpret_cast<const f32x4*>(po + ks * 32 + kq * 8 + 4);
                af[ks] = pack8(v0, v1);
            }
            #pragma unroll
            for (int ks = 0; ks < 4; ++ks)
                #pragma unroll
                for (int nt = 0; nt < 8; ++nt) {
                    short8 b = *reinterpret_cast<const short8*>(&Wl[(((ks + 8) * 8 + nt) * 64 + l) * 8]);
                    acc[nt] = __builtin_amdgcn_mfma_f32_16x16x32_bf16(af[ks], b, acc[nt], 0, 0, 0);
                }
        }

        #pragma unroll
        for (int p = 0; p < 2; ++p) {
            #pragma unroll
            for (int nt2 = 0; nt2 < 4; ++nt2) {
                int nt = p * 4 + nt2;
                #pragma unroll
                for (int j = 0; j < 4; ++j) {
                    int row = kq * 4 + j;
                    float hv = fmaxf(acc[nt][j] + bias[nt], 0.0f);
                    hw[row * 68 + nt2 * 16 + r16] = f2bf(hv);
                }
            }
            asm volatile("s_waitcnt lgkmcnt(0)" ::: "memory");
            #pragma unroll
            for (int it = 0; it < 2; ++it) {
                short8 hv = *reinterpret_cast<const short8*>(&hw[(l >> 2) * 68 + (l & 3) * 16 + it * 8]);
                *reinterpret_cast<short8*>(
                    &hbuf[(size_t)(ch * 16 + (l >> 2)) * 128 + p * 64 + (l & 3) * 16 + it * 8]) = hv;
            }
            asm volatile("s_waitcnt lgkmcnt(0)" ::: "memory");
        }
    }
}

// fused_k: role-split blocks. blocks [0,PBLKS): new_p GEMM (round-9 gemm2_p, proven).
// blocks [PBLKS, PBLKS+HBLKS): CSR gather-sum of h rows -> Hs/Ho (zero atomics).
__global__ __launch_bounds__(512, 4) void fused_k(
    const ushort_t* __restrict__ hbuf,
    const ushort_t* __restrict__ W1b_p, const float* __restrict__ b1b,
    float* __restrict__ new_p,
    const int* __restrict__ soff, const int* __restrict__ slist,
    const int* __restrict__ ooff, const int* __restrict__ olist,
    ushort_t* __restrict__ Hs, ushort_t* __restrict__ Ho)
{
    __shared__ __align__(16) ushort_t Wl[16384];
    const int tid = threadIdx.x;
    const int l = tid & 63;
    const int w = tid >> 6;

    if (blockIdx.x < PBLKS) {
        const int q = l >> 5;
        const int r32 = l & 31;
        #pragma unroll
        for (int i = 0; i < 4; ++i) {
            int idx = i * 512 + tid;
            int blk = idx >> 6;
            int li = idx & 63;
            reinterpret_cast<short8*>(Wl)[idx] =
                *reinterpret_cast<const short8*>(&W1b_p[(((blk >> 2) * 12 + 4 + (blk & 3)) * 64 + li) * 8]);
        }
        __syncthreads();

        float bias[4];
        #pragma unroll
        for (int nt = 0; nt < 4; ++nt) bias[nt] = b1b[128 + (nt << 5) + r32];

        for (int c = blockIdx.x; c < NCH1; c += PBLKS) {
            int trow = c * 256 + w * 32 + r32;
            int tr = trow < T_N ? trow : T_N - 1;

            short8 af[8];
            #pragma unroll
            for (int ks = 0; ks < 8; ++ks)
                af[ks] = *reinterpret_cast<const short8*>(&hbuf[(size_t)tr * 128 + (ks << 4) + (q << 3)]);

            f32x16 acc[4] = {};
            #pragma unroll
            for (int ks = 0; ks < 8; ++ks) {
                #pragma unroll
                for (int nt2 = 0; nt2 < 4; ++nt2) {
                    short8 bf = *reinterpret_cast<const short8*>(&Wl[(((ks << 2) + nt2) * 64 + l) * 8]);
                    acc[nt2] = __builtin_amdgcn_mfma_f32_32x32x16_bf16(af[ks], bf, acc[nt2], 0, 0, 0);
                }
            }
            #pragma unroll
            for (int nt2 = 0; nt2 < 4; ++nt2) {
                #pragma unroll
                for (int r = 0; r < 16; ++r) {
                    int rl = (r & 3) + ((r >> 2) << 3) + (q << 2);
                    int trow2 = c * 256 + w * 32 + rl;
                    if (trow2 < T_N)
                        new_p[(size_t)trow2 * 128 + (nt2 << 5) + r32] = acc[nt2][r] + bias[nt2];
                }
            }
        }
    } else {
        // h-role: one wave per object; lane l owns cols {2l, 2l+1}
        for (int o = (blockIdx.x - PBLKS) * 8 + w; o < O_N; o += HBLKS * 8) {
            float a0 = 0.f, a1 = 0.f;
            int b = soff[o], e = soff[o + 1];
            for (int j = b; j < e; ++j) {
                int t = slist[j];
                unsigned v = *reinterpret_cast<const unsigned*>(&hbuf[(size_t)t * 128 + 2 * l]);
                union { float f; unsigned u; } x0, x1;
                x0.u = v << 16;
                x1.u = v & 0xffff0000u;
                a0 += x0.f; a1 += x1.f;
            }
            reinterpret_cast<unsigned*>(Hs + (size_t)o * 128)[l] =
                (unsigned)f2bf(a0) | ((unsigned)f2bf(a1) << 16);

            a0 = 0.f; a1 = 0.f;
            b = ooff[o]; e = ooff[o + 1];
            for (int j = b; j < e; ++j) {
                int t = olist[j];
                unsigned v = *reinterpret_cast<const unsigned*>(&hbuf[(size_t)t * 128 + 2 * l]);
                union { float f; unsigned u; } x0, x1;
                x0.u = v << 16;
                x1.u = v & 0xffff0000u;
                a0 += x0.f; a1 += x1.f;
            }
            reinterpret_cast<unsigned*>(Ho + (size_t)o * 128)[l] =
                (unsigned)f2bf(a0) | ((unsigned)f2bf(a1) << 16);
        }
    }
}

// pooled_k (round 8, proven): pooled = [Hs|Ho]@[W1b_s;W1b_o] + cs*bs + co*bo, /max(cs+co,1)
__global__ __launch_bounds__(512, 4) void pooled_k(
    const ushort_t* __restrict__ Hs, const ushort_t* __restrict__ Ho,
    const float* __restrict__ cs, const float* __restrict__ co,
    const ushort_t* __restrict__ Wso_p, const float* __restrict__ b1b,
    ushort_t* __restrict__ pooled_bf)
{
    __shared__ __align__(16) ushort_t Wl[32768];
    const int tid = threadIdx.x;
    const int l = tid & 63;
    const int w = tid >> 6;
    const int q = l >> 5;
    const int r32 = l & 31;

    #pragma unroll
    for (int i = 0; i < 8; ++i)
        reinterpret_cast<short8*>(Wl)[i * 512 + tid] =
            reinterpret_cast<const short8*>(Wso_p)[i * 512 + tid];
    __syncthreads();

    float bs[4], bo[4];
    #pragma unroll
    for (int nt = 0; nt < 4; ++nt) {
        bs[nt] = b1b[(nt << 5) + r32];
        bo[nt] = b1b[256 + (nt << 5) + r32];
    }

    for (int c = blockIdx.x; c < NCH3; c += gridDim.x) {
        int row = c * 256 + w * 32 + r32;
        int rr = row < O_N ? row : O_N - 1;

        short8 af[16];
        #pragma unroll
        for (int ks = 0; ks < 8; ++ks)
            af[ks] = *reinterpret_cast<const short8*>(&Hs[(size_t)rr * 128 + (ks << 4) + (q << 3)]);
        #pragma unroll
        for (int ks = 0; ks < 8; ++ks)
            af[8 + ks] = *reinterpret_cast<const short8*>(&Ho[(size_t)rr * 128 + (ks << 4) + (q << 3)]);

        f32x16 acc[4] = {};
        #pragma unroll
        for (int ks = 0; ks < 16; ++ks) {
            #pragma unroll
            for (int nt = 0; nt < 4; ++nt) {
                short8 bf = *reinterpret_cast<const short8*>(&Wl[(((ks << 2) + nt) * 64 + l) * 8]);
                acc[nt] = __builtin_amdgcn_mfma_f32_32x32x16_bf16(af[ks], bf, acc[nt], 0, 0, 0);
            }
        }

        #pragma unroll
        for (int r = 0; r < 16; ++r) {
            int rl = (r & 3) + ((r >> 2) << 3) + (q << 2);
            int row2 = c * 256 + w * 32 + rl;
            if (row2 < O_N) {
                float csv = cs[row2], cov = co[row2];
                float inv = 1.0f / fmaxf(csv + cov, 1.0f);
                #pragma unroll
                for (int nt = 0; nt < 4; ++nt) {
                    float val = (acc[nt][r] + csv * bs[nt] + cov * bo[nt]) * inv;
                    pooled_bf[(size_t)row2 * 128 + (nt << 5) + r32] = f2bf(val);
                }
            }
        }
    }
}

// objects_nd (round 8, proven): pooled_bf (normalized) -> relu(x@W2a+b2a)@W2b+b2b
__global__ __launch_bounds__(512, 2) void objects_nd(
    const ushort_t* __restrict__ pooled_bf,
    const ushort_t* __restrict__ W2a_p, const float* __restrict__ b2a,
    const ushort_t* __restrict__ W2b_p, const float* __restrict__ b2b,
    float* __restrict__ outp)
{
    __shared__ __align__(16) ushort_t Wa[16384];
    __shared__ __align__(16) ushort_t Wb[16384];
    __shared__ __align__(16) ushort_t hx[8][4096];
    const int tid = threadIdx.x;
    const int l = tid & 63;
    const int w = tid >> 6;
    const int q = l >> 5;
    const int r32 = l & 31;

    {
        const short8* sa = reinterpret_cast<const short8*>(W2a_p);
        const short8* sb = reinterpret_cast<const short8*>(W2b_p);
        short8* da = reinterpret_cast<short8*>(Wa);
        short8* db = reinterpret_cast<short8*>(Wb);
        #pragma unroll
        for (int i = 0; i < 4; ++i) { da[i * 512 + tid] = sa[i * 512 + tid]; db[i * 512 + tid] = sb[i * 512 + tid]; }
    }
    __syncthreads();

    float ba[4], bb[4];
    #pragma unroll
    for (int nt = 0; nt < 4; ++nt) { ba[nt] = b2a[(nt << 5) + r32]; bb[nt] = b2b[(nt << 5) + r32]; }

    for (int c = blockIdx.x; c < NCH3; c += gridDim.x) {
        int row = c * 256 + w * 32 + r32;
        int rr = row < O_N ? row : O_N - 1;

        short8 af[8];
        #pragma unroll
        for (int ks = 0; ks < 8; ++ks)
            af[ks] = *reinterpret_cast<const short8*>(&pooled_bf[(size_t)rr * 128 + (ks << 4) + (q << 3)]);

        f32x16 acc[4] = {};
        #pragma unroll
        for (int ks = 0; ks < 8; ++ks) {
            #pragma unroll
            for (int nt = 0; nt < 4; ++nt) {
                short8 bf = *reinterpret_cast<const short8*>(&Wa[(((ks << 2) + nt) * 64 + l) * 8]);
                acc[nt] = __builtin_amdgcn_mfma_f32_32x32x16_bf16(af[ks], bf, acc[nt], 0, 0, 0);
            }
        }

        char* hxw = (char*)&hx[w][0];
        #pragma unroll
        for (int nt = 0; nt < 4; ++nt) {
            #pragma unroll
            for (int r = 0; r < 16; ++r) {
                int rl = (r & 3) + ((r >> 2) << 3) + (q << 2);
                float hv = fmaxf(acc[nt][r] + ba[nt], 0.0f);
                int off = rl * 256 + (((nt << 5) + r32) << 1);
                off ^= (rl & 15) << 4;
                *(ushort_t*)(hxw + off) = f2bf(hv);
            }
        }
        __syncthreads();

        short8 af2[8];
        #pragma unroll
        for (int ks = 0; ks < 8; ++ks) {
            int off = r32 * 256 + (ks << 5) + (q << 4);
            off ^= (r32 & 15) << 4;
            af2[ks] = *reinterpret_cast<const short8*>(hxw + off);
        }

        f32x16 acc2[4] = {};
        #pragma unroll
        for (int ks = 0; ks < 8; ++ks) {
            #pragma unroll
            for (int nt = 0; nt < 4; ++nt) {
                short8 bf = *reinterpret_cast<const short8*>(&Wb[(((ks << 2) + nt) * 64 + l) * 8]);
                acc2[nt] = __builtin_amdgcn_mfma_f32_32x32x16_bf16(af2[ks], bf, acc2[nt], 0, 0, 0);
            }
        }

        #pragma unroll
        for (int nt = 0; nt < 4; ++nt) {
            #pragma unroll
            for (int r = 0; r < 16; ++r) {
                int rl = (r & 3) + ((r >> 2) << 3) + (q << 2);
                int row2 = c * 256 + w * 32 + rl;
                if (row2 < O_N) outp[(size_t)row2 * 128 + (nt << 5) + r32] = acc2[nt][r] + bb[nt];
            }
        }
        __syncthreads();
    }
}

// ---------------- fallback path (round-1, known-good) ----------------
__device__ __forceinline__ void stage_w(const unsigned short* __restrict__ src,
                                        unsigned short* __restrict__ dst, int tid) {
    const short8* s = reinterpret_cast<const short8*>(src);
    short8* d = reinterpret_cast<short8*>(dst);
    d[tid] = s[tid];
    d[tid + 256] = s[tid + 256];
}

__global__ __launch_bounds__(256, 2) void triples_kernel(
    const float* __restrict__ obj_vecs, const float* __restrict__ pred_vecs,
    const int* __restrict__ edges,
    const unsigned short* __restrict__ W1a_p, const float* __restrict__ b1a,
    const unsigned short* __restrict__ W1b_p, const float* __restrict__ b1b,
    float* __restrict__ pooled, float* __restrict__ new_p, float* __restrict__ counts)
{
    __shared__ __align__(16) unsigned short Apack[24576];
    __shared__ __align__(16) unsigned short Wbuf[2][4096];
    __shared__ int sseg[64], oseg[64];
    const int tid = threadIdx.x;
    const int lane = tid & 63;
    const int w = tid >> 6;
    const int t0 = blockIdx.x * 64;
    if (tid < 64) {
        int s = edges[2 * (t0 + tid)];
        int o = edges[2 * (t0 + tid) + 1];
        sseg[tid] = s; oseg[tid] = o;
        atomicAdd(&counts[s], 1.0f);
        atomicAdd(&counts[o], 1.0f);
    }
    __syncthreads();
    for (int it = 0; it < 24; ++it) {
        int idx = it * 256 + tid;
        int r = idx / 96;
        int c = (idx % 96) * 4;
        const float* srcp;
        if (c < 128)      srcp = obj_vecs  + (size_t)sseg[r] * 128 + c;
        else if (c < 256) srcp = pred_vecs + (size_t)(t0 + r) * 128 + (c - 128);
        else              srcp = obj_vecs  + (size_t)oseg[r] * 128 + (c - 256);
        f32x4 v = *reinterpret_cast<const f32x4*>(srcp);
        int off = (((r >> 4) * 12 + (c >> 5)) << 9)
                + (((r & 15) | (((c & 31) >> 3) << 4)) << 3) + (c & 7);
        Apack[off + 0] = f2bf(v[0]); Apack[off + 1] = f2bf(v[1]);
        Apack[off + 2] = f2bf(v[2]); Apack[off + 3] = f2bf(v[3]);
    }
    stage_w(W1a_p, Wbuf[0], tid);
    __syncthreads();
    f32x4 acc[8];
    #pragma unroll
    for (int n = 0; n < 8; ++n) acc[n] = (f32x4){0.f, 0.f, 0.f, 0.f};
    for (int kk = 0; kk < 12; ++kk) {
        if (kk < 11) stage_w(W1a_p + (kk + 1) * 4096, Wbuf[(kk + 1) & 1], tid);
        short8 a = *reinterpret_cast<const short8*>(&Apack[((w * 12 + kk) << 9) + (lane << 3)]);
        const unsigned short* wb = Wbuf[kk & 1];
        #pragma unroll
        for (int n = 0; n < 8; ++n) {
            short8 b = *reinterpret_cast<const short8*>(&wb[((n << 6) + lane) << 3]);
            acc[n] = __builtin_amdgcn_mfma_f32_16x16x32_bf16(a, b, acc[n], 0, 0, 0);
        }
        __syncthreads();
    }
    #pragma unroll
    for (int n = 0; n < 8; ++n) {
        int col = (n << 4) + (lane & 15);
        float bias = b1a[col];
        int base = ((w * 4 + (col >> 5)) << 9) + (col & 7);
        int chi = ((col & 31) >> 3) << 4;
        #pragma unroll
        for (int jj = 0; jj < 4; ++jj) {
            int rloc = ((lane >> 4) << 2) + jj;
            float hv = acc[n][jj] + bias;
            hv = hv > 0.f ? hv : 0.f;
            Apack[base + ((rloc | chi) << 3)] = f2bf(hv);
        }
    }
    for (int g = 0; g < 3; ++g) {
        const unsigned short* Wsrc = W1b_p + g * 16384;
        stage_w(Wsrc, Wbuf[0], tid);
        __syncthreads();
        f32x4 acc2[8];
        #pragma unroll
        for (int n = 0; n < 8; ++n) acc2[n] = (f32x4){0.f, 0.f, 0.f, 0.f};
        for (int kk = 0; kk < 4; ++kk) {
            if (kk < 3) stage_w(Wsrc + (kk + 1) * 4096, Wbuf[(kk + 1) & 1], tid);
            short8 a = *reinterpret_cast<const short8*>(&Apack[((w * 4 + kk) << 9) + (lane << 3)]);
            const unsigned short* wb = Wbuf[kk & 1];
            #pragma unroll
            for (int n = 0; n < 8; ++n) {
                short8 b = *reinterpret_cast<const short8*>(&wb[((n << 6) + lane) << 3]);
                acc2[n] = __builtin_amdgcn_mfma_f32_16x16x32_bf16(a, b, acc2[n], 0, 0, 0);
            }
            __syncthreads();
        }
        #pragma unroll
        for (int n = 0; n < 8; ++n) {
            int col = (n << 4) + (lane & 15);
            float bias = b1b[g * 128 + col];
            #pragma unroll
            for (int jj = 0; jj < 4; ++jj) {
                int rloc = (w << 4) + ((lane >> 4) << 2) + jj;
                float val = acc2[n][jj] + bias;
                if (g == 1) {
                    new_p[(size_t)(t0 + rloc) * 128 + col] = val;
                } else {
                    int seg = (g == 0) ? sseg[rloc] : oseg[rloc];
                    atomicAdd(&pooled[(size_t)seg * 128 + col], val);
                }
            }
        }
    }
}

__global__ __launch_bounds__(256, 2) void objects_kernel(
    const float* __restrict__ counts,
    const unsigned short* __restrict__ W2a_p, const float* __restrict__ b2a,
    const unsigned short* __restrict__ W2b_p, const float* __restrict__ b2b,
    float* __restrict__ inout)
{
    __shared__ __align__(16) unsigned short Apack[8192];
    __shared__ __align__(16) unsigned short Hpack[8192];
    __shared__ __align__(16) unsigned short Wbuf[2][4096];
    const int tid = threadIdx.x;
    const int lane = tid & 63;
    const int w = tid >> 6;
    const int r0 = blockIdx.x * 64;
    for (int it = 0; it < 8; ++it) {
        int idx = it * 256 + tid;
        int r = idx >> 5;
        int c = (idx & 31) << 2;
        int row = r0 + r;
        float vals[4] = {0.f, 0.f, 0.f, 0.f};
        if (row < O_N) {
            f32x4 v = *reinterpret_cast<const f32x4*>(&inout[(size_t)row * 128 + c]);
            float inv = 1.0f / fmaxf(counts[row], 1.0f);
            vals[0] = v[0] * inv; vals[1] = v[1] * inv;
            vals[2] = v[2] * inv; vals[3] = v[3] * inv;
        }
        int off = (((r >> 4) * 4 + (c >> 5)) << 9)
                + (((r & 15) | (((c & 31) >> 3) << 4)) << 3) + (c & 7);
        Apack[off + 0] = f2bf(vals[0]); Apack[off + 1] = f2bf(vals[1]);
        Apack[off + 2] = f2bf(vals[2]); Apack[off + 3] = f2bf(vals[3]);
    }
    stage_w(W2a_p, Wbuf[0], tid);
    __syncthreads();
    f32x4 acc[8];
    #pragma unroll
    for (int n = 0; n < 8; ++n) acc[n] = (f32x4){0.f, 0.f, 0.f, 0.f};
    for (int kk = 0; kk < 4; ++kk) {
        if (kk < 3) stage_w(W2a_p + (kk + 1) * 4096, Wbuf[(kk + 1) & 1], tid);
        short8 a = *reinterpret_cast<const short8*>(&Apack[((w * 4 + kk) << 9) + (lane << 3)]);
        const unsigned short* wb = Wbuf[kk & 1];
        #pragma unroll
        for (int n = 0; n < 8; ++n) {
            short8 b = *reinterpret_cast<const short8*>(&wb[((n << 6) + lane) << 3]);
            acc[n] = __builtin_amdgcn_mfma_f32_16x16x32_bf16(a, b, acc[n], 0, 0, 0);
        }
        __syncthreads();
    }
    #pragma unroll
    for (int n = 0; n < 8; ++n) {
        int col = (n << 4) + (lane & 15);
        float bias = b2a[col];
        int base = ((w * 4 + (col >> 5)) << 9) + (col & 7);
        int chi = ((col & 31) >> 3) << 4;
        #pragma unroll
        for (int jj = 0; jj < 4; ++jj) {
            int rloc = ((lane >> 4) << 2) + jj;
            float hv = acc[n][jj] + bias;
            hv = hv > 0.f ? hv : 0.f;
            Hpack[base + ((rloc | chi) << 3)] = f2bf(hv);
        }
    }
    stage_w(W2b_p, Wbuf[0], tid);
    __syncthreads();
    f32x4 acc2[8];
    #pragma unroll
    for (int n = 0; n < 8; ++n) acc2[n] = (f32x4){0.f, 0.f, 0.f, 0.f};
    for (int kk = 0; kk < 4; ++kk) {
        if (kk < 3) stage_w(W2b_p + (kk + 1) * 4096, Wbuf[(kk + 1) & 1], tid);
        short8 a = *reinterpret_cast<const short8*>(&Hpack[((w * 4 + kk) << 9) + (lane << 3)]);
        const unsigned short* wb = Wbuf[kk & 1];
        #pragma unroll
        for (int n = 0; n < 8; ++n) {
            short8 b = *reinterpret_cast<const short8*>(&wb[((n << 6) + lane) << 3]);
            acc2[n] = __builtin_amdgcn_mfma_f32_16x16x32_bf16(a, b, acc2[n], 0, 0, 0);
        }
        __syncthreads();
    }
    #pragma unroll
    for (int n = 0; n < 8; ++n) {
        int col = (n << 4) + (lane & 15);
        float bias = b2b[col];
        #pragma unroll
        for (int jj = 0; jj < 4; ++jj) {
            int rloc = (w << 4) + ((lane >> 4) << 2) + jj;
            int row = r0 + rloc;
            if (row < O_N) inout[(size_t)row * 128 + col] = acc2[n][jj] + bias;
        }
    }
}

extern "C" void kernel_launch(void* const* d_in, const int* in_sizes, int n_in,
                              void* d_out, int out_size, void* d_ws, size_t ws_size,
                              hipStream_t stream)
{
    const float* obj   = (const float*)d_in[0];
    const float* pred  = (const float*)d_in[1];
    const int*   edges = (const int*)d_in[2];
    const float* W1a = (const float*)d_in[3];
    const float* b1a = (const float*)d_in[4];
    const float* W1b = (const float*)d_in[5];
    const float* b1b = (const float*)d_in[6];
    const float* W2a = (const float*)d_in[7];
    const float* b2a = (const float*)d_in[8];
    const float* W2b = (const float*)d_in[9];
    const float* b2b = (const float*)d_in[10];

    float* out    = (float*)d_out;
    float* new_p  = out + (size_t)O_N * 128;   // T x 128

    // Hs/Ho scratch lives in the (not-yet-written) new_obj region: 2 x 25.6 MB = 51.2 MB
    ushort_t* Hs = (ushort_t*)d_out;
    ushort_t* Ho = Hs + (size_t)O_N * 128;

    uintptr_t wsbase = (uintptr_t)d_ws;
    float* cs = (float*)wsbase;               // also fallback's counts
    float* co = cs + O_N;
    int* soff = (int*)(co + O_N);             // O_N+1
    int* ooff = soff + O_N + 1;               // O_N+1
    int* scur = ooff + O_N + 1;               // O_N
    int* ocur = scur + O_N;                   // O_N
    int* slist = ocur + O_N;                  // T_N
    int* olist = slist + T_N;                 // T_N
    uintptr_t p = ((uintptr_t)(olist + T_N) + 255) & ~(uintptr_t)255;
    ushort_t* pooled_bf = (ushort_t*)p;  p += (size_t)O_N * 128 * 2;    // 25.6 MB
    ushort_t* W1a_p = (ushort_t*)p;  p += (size_t)49152 * 2;            // 16x16 pack (gemm1)
    ushort_t* W1b_p = (ushort_t*)p;  p += (size_t)49152 * 2;            // 32x32 pack (p-role)
    ushort_t* W2a_p = (ushort_t*)p;  p += (size_t)16384 * 2;
    ushort_t* W2b_p = (ushort_t*)p;  p += (size_t)16384 * 2;
    ushort_t* Wso_p = (ushort_t*)p;  p += (size_t)32768 * 2;            // K=256 pack (pooled)
    ushort_t* hbuf  = (ushort_t*)p;  p += (size_t)T_N * 128 * 2;        // 102.4 MB row-major
    size_t need = p - wsbase;

    if (ws_size >= need) {
        hipMemsetAsync(cs, 0, (size_t)O_N * 2 * sizeof(float), stream);  // cs+co

        pack_b<<<192, 256, 0, stream>>>(W1a, W1a_p, 384, 8, 128, 0);
        pack_b32<<<192, 256, 0, stream>>>(W1b, W1b_p, 8, 12, 384, 0);
        pack_b32<<<64, 256, 0, stream>>>(W2a, W2a_p, 8, 4, 128, 0);
        pack_b32<<<64, 256, 0, stream>>>(W2b, W2b_p, 8, 4, 128, 0);
        pack_bso<<<128, 256, 0, stream>>>(W1b, Wso_p);

        counts2_k<<<(T_N + 255) / 256, 256, 0, stream>>>(edges, cs, co);
        scan_k<<<2, 1024, 0, stream>>>(cs, soff, scur, co, ooff, ocur);
        scatter_k<<<(T_N + 255) / 256, 256, 0, stream>>>(edges, scur, ocur, slist, olist);

        gemm1_k<<<256, 1024, 0, stream>>>(obj, pred, edges, W1a_p, b1a, hbuf);
        fused_k<<<PBLKS + HBLKS, 512, 0, stream>>>(hbuf, W1b_p, b1b, new_p,
                                                   soff, slist, ooff, olist, Hs, Ho);
        pooled_k<<<391, 512, 0, stream>>>(Hs, Ho, cs, co, Wso_p, b1b, pooled_bf);
        objects_nd<<<391, 512, 0, stream>>>(pooled_bf, W2a_p, b2a, W2b_p, b2b, out);
    } else {
        // fallback: round-1 fused path (correct, slower); pooled f32 in d_out
        float* pooled = out;
        float* counts = cs;
        hipMemsetAsync(counts, 0, (size_t)O_N * sizeof(float), stream);
        hipMemsetAsync(pooled, 0, (size_t)O_N * 128 * sizeof(float), stream);

        pack_b<<<192, 256, 0, stream>>>(W1a, W1a_p, 384, 8, 128, 0);
        pack_b<<<64, 256, 0, stream>>>(W1b, W1b_p,         128, 8, 384, 0);
        pack_b<<<64, 256, 0, stream>>>(W1b, W1b_p + 16384, 128, 8, 384, 128);
        pack_b<<<64, 256, 0, stream>>>(W1b, W1b_p + 32768, 128, 8, 384, 256);
        pack_b<<<64, 256, 0, stream>>>(W2a, W2a_p, 128, 8, 128, 0);
        pack_b<<<64, 256, 0, stream>>>(W2b, W2b_p, 128, 8, 128, 0);

        triples_kernel<<<T_N / 64, 256, 0, stream>>>(obj, pred, edges,
                                                     W1a_p, b1a, W1b_p, b1b,
                                                     pooled, new_p, counts);
        objects_kernel<<<(O_N + 63) / 64, 256, 0, stream>>>(counts, W2a_p, b2a, W2b_p, b2b, out);
    }
}

// Round 12
// 454.281 us; speedup vs baseline: 2.0594x; 2.0594x over previous
//
#include <hip/hip_runtime.h>
#include <hip/hip_bf16.h>
#include <stdint.h>

#define O_N 100000
#define T_N 400000
#define NCH1 1563   // ceil(400000/256) for gemm2
#define NCH3 391    // ceil(100000/256)
#define NCHW 25000  // 400000/16 wave-chunks for gemm1

typedef __attribute__((ext_vector_type(8))) short short8;
typedef __attribute__((ext_vector_type(4))) float f32x4;
typedef __attribute__((ext_vector_type(16))) float f32x16;
typedef unsigned short ushort_t;

__device__ __forceinline__ unsigned short f2bf(float x) {
    union { float f; unsigned u; } v; v.f = x;
    unsigned u = v.u;
    unsigned rounded = u + 0x7FFF + ((u >> 16) & 1);
    return (unsigned short)(rounded >> 16);
}

__device__ __forceinline__ short8 pack8(f32x4 a, f32x4 b) {
    short8 t;
    t[0] = (short)f2bf(a[0]); t[1] = (short)f2bf(a[1]);
    t[2] = (short)f2bf(a[2]); t[3] = (short)f2bf(a[3]);
    t[4] = (short)f2bf(b[0]); t[5] = (short)f2bf(b[1]);
    t[6] = (short)f2bf(b[2]); t[7] = (short)f2bf(b[3]);
    return t;
}

// merged weight pack: one launch packs W1a (16x16 frags) + W1b/W2a/W2b (32x32 frags)
// item ranges: [0,49152) W1a16 | [49152,98304) W1b32 | [98304,114688) W2a32 | [114688,131072) W2b32
__global__ __launch_bounds__(256) void pack_all(
    const float* __restrict__ W1a, const float* __restrict__ W1b,
    const float* __restrict__ W2a, const float* __restrict__ W2b,
    ushort_t* __restrict__ W1a_p, ushort_t* __restrict__ W1b_p,
    ushort_t* __restrict__ W2a_p, ushort_t* __restrict__ W2b_p)
{
    int idx = blockIdx.x * 256 + threadIdx.x;
    if (idx < 49152) {
        // 16x16x32 B-frag pack of W1a (K=384, Ntiles=8, ldw=128)
        int j = idx & 7;
        int lane = (idx >> 3) & 63;
        int t2 = idx >> 9;
        int ntile = t2 & 7;
        int kstep = t2 >> 3;
        int k = kstep * 32 + ((lane >> 4) << 3) + j;
        int n = (ntile << 4) + (lane & 15);
        W1a_p[idx] = f2bf(W1a[(size_t)k * 128 + n]);
    } else if (idx < 98304) {
        // 32x32x16 B-frag pack of W1b (Ksteps=8, NT=12, ldw=384)
        int i = idx - 49152;
        int j = i & 7;
        int lane = (i >> 3) & 63;
        int t2 = i >> 9;
        int nt = t2 % 12;
        int ks = t2 / 12;
        int k = ks * 16 + ((lane >> 5) << 3) + j;
        int n = (nt << 5) + (lane & 31);
        W1b_p[i] = f2bf(W1b[(size_t)k * 384 + n]);
    } else {
        // 32x32x16 B-frag pack of W2a / W2b (Ksteps=8, NT=4, ldw=128)
        int i = idx - 98304;
        const float* W = (i < 16384) ? W2a : W2b;
        ushort_t* out = (i < 16384) ? W2a_p : W2b_p;
        int ii = i & 16383;
        int j = ii & 7;
        int lane = (ii >> 3) & 63;
        int t2 = ii >> 9;
        int nt = t2 & 3;
        int ks = t2 >> 2;
        int k = ks * 16 + ((lane >> 5) << 3) + j;
        int n = (nt << 5) + (lane & 31);
        out[ii] = f2bf(W[(size_t)k * 128 + n]);
    }
}

// B-fragment pack for mfma_f32_16x16x32_bf16 (fallback path only)
__global__ void pack_b(const float* __restrict__ W, unsigned short* __restrict__ out,
                       int K, int Ntiles, int ldw, int col0) {
    int idx = blockIdx.x * 256 + threadIdx.x;
    int total = K * Ntiles * 16;
    if (idx >= total) return;
    int j = idx & 7;
    int lane = (idx >> 3) & 63;
    int t2 = idx >> 9;
    int ntile = t2 % Ntiles;
    int kstep = t2 / Ntiles;
    int k = kstep * 32 + ((lane >> 4) << 3) + j;
    int n = (ntile << 4) + (lane & 15);
    out[idx] = f2bf(W[(size_t)k * ldw + col0 + n]);
}

// segment counts
__global__ void counts_k(const int* __restrict__ edges, float* __restrict__ counts) {
    int idx = blockIdx.x * 256 + threadIdx.x;
    if (idx >= T_N) return;
    int2 e = ((const int2*)edges)[idx];
    atomicAdd(&counts[e.x], 1.0f);
    atomicAdd(&counts[e.y], 1.0f);
}

// K1 (round 7, proven): 16 waves/block, zero steady-state barriers.
__global__ __launch_bounds__(1024, 4) void gemm1_k(
    const float* __restrict__ obj_vecs, const float* __restrict__ pred_vecs,
    const int* __restrict__ edges,
    const ushort_t* __restrict__ W1a_p, const float* __restrict__ b1a,
    ushort_t* __restrict__ hbuf)
{
    __shared__ __align__(16) ushort_t Wl[49152];
    __shared__ __align__(16) ushort_t hx[16][1088];
    const int tid = threadIdx.x;
    const int l = tid & 63;
    const int w = tid >> 6;
    const int r16 = l & 15;
    const int kq = l >> 4;

    {
        const short8* s = reinterpret_cast<const short8*>(W1a_p);
        short8* d = reinterpret_cast<short8*>(Wl);
        #pragma unroll
        for (int i = 0; i < 6; ++i) d[i * 1024 + tid] = s[i * 1024 + tid];
    }
    __syncthreads();

    float bias[8];
    #pragma unroll
    for (int nt = 0; nt < 8; ++nt) bias[nt] = b1a[nt * 16 + r16];

    ushort_t* hw = hx[w];
    const int2* e2 = (const int2*)edges;
    const int stride = gridDim.x * 16;

    for (int ch = blockIdx.x * 16 + w; ch < NCHW; ch += stride) {
        int tri = ch * 16 + r16;
        int2 e = e2[tri];
        const float* ps = obj_vecs  + (size_t)e.x * 128;
        const float* pp = pred_vecs + (size_t)tri * 128;
        const float* po = obj_vecs  + (size_t)e.y * 128;

        f32x4 acc[8];
        #pragma unroll
        for (int nt = 0; nt < 8; ++nt) acc[nt] = (f32x4){0.f, 0.f, 0.f, 0.f};

        {
            short8 af[4];
            #pragma unroll
            for (int ks = 0; ks < 4; ++ks) {
                f32x4 v0 = *reinterpret_cast<const f32x4*>(ps + ks * 32 + kq * 8);
                f32x4 v1 = *reinterpret_cast<const f32x4*>(ps + ks * 32 + kq * 8 + 4);
                af[ks] = pack8(v0, v1);
            }
            #pragma unroll
            for (int ks = 0; ks < 4; ++ks)
                #pragma unroll
                for (int nt = 0; nt < 8; ++nt) {
                    short8 b = *reinterpret_cast<const short8*>(&Wl[((ks * 8 + nt) * 64 + l) * 8]);
                    acc[nt] = __builtin_amdgcn_mfma_f32_16x16x32_bf16(af[ks], b, acc[nt], 0, 0, 0);
                }
        }
        {
            short8 af[4];
            #pragma unroll
            for (int ks = 0; ks < 4; ++ks) {
                f32x4 v0 = *reinterpret_cast<const f32x4*>(pp + ks * 32 + kq * 8);
                f32x4 v1 = *reinterpret_cast<const f32x4*>(pp + ks * 32 + kq * 8 + 4);
                af[ks] = pack8(v0, v1);
            }
            #pragma unroll
            for (int ks = 0; ks < 4; ++ks)
                #pragma unroll
                for (int nt = 0; nt < 8; ++nt) {
                    short8 b = *reinterpret_cast<const short8*>(&Wl[(((ks + 4) * 8 + nt) * 64 + l) * 8]);
                    acc[nt] = __builtin_amdgcn_mfma_f32_16x16x32_bf16(af[ks], b, acc[nt], 0, 0, 0);
                }
        }
        {
            short8 af[4];
            #pragma unroll
            for (int ks = 0; ks < 4; ++ks) {
                f32x4 v0 = *reinterpret_cast<const f32x4*>(po + ks * 32 + kq * 8);
                f32x4 v1 = *reinterpret_cast<const f32x4*>(po + ks * 32 + kq * 8 + 4);
                af[ks] = pack8(v0, v1);
            }
            #pragma unroll
            for (int ks = 0; ks < 4; ++ks)
                #pragma unroll
                for (int nt = 0; nt < 8; ++nt) {
                    short8 b = *reinterpret_cast<const short8*>(&Wl[(((ks + 8) * 8 + nt) * 64 + l) * 8]);
                    acc[nt] = __builtin_amdgcn_mfma_f32_16x16x32_bf16(af[ks], b, acc[nt], 0, 0, 0);
                }
        }

        #pragma unroll
        for (int p = 0; p < 2; ++p) {
            #pragma unroll
            for (int nt2 = 0; nt2 < 4; ++nt2) {
                int nt = p * 4 + nt2;
                #pragma unroll
                for (int j = 0; j < 4; ++j) {
                    int row = kq * 4 + j;
                    float hv = fmaxf(acc[nt][j] + bias[nt], 0.0f);
                    hw[row * 68 + nt2 * 16 + r16] = f2bf(hv);
                }
            }
            asm volatile("s_waitcnt lgkmcnt(0)" ::: "memory");
            #pragma unroll
            for (int it = 0; it < 2; ++it) {
                short8 hv = *reinterpret_cast<const short8*>(&hw[(l >> 2) * 68 + (l & 3) * 16 + it * 8]);
                *reinterpret_cast<short8*>(
                    &hbuf[(size_t)(ch * 16 + (l >> 2)) * 128 + p * 64 + (l & 3) * 16 + it * 8]) = hv;
            }
            asm volatile("s_waitcnt lgkmcnt(0)" ::: "memory");
        }
    }
}

// K2 (round 7, proven best): h @ W1b + b1b -> 3 nt-groups
// {new_s pk-atomic, new_p store, new_o pk-atomic}, W1b resident in 96 KB LDS.
// Atomic latency hides under the p-group GEMM + stores in the same wave stream.
__global__ __launch_bounds__(512, 2) void gemm2_k(
    const ushort_t* __restrict__ hbuf, const int* __restrict__ edges,
    const ushort_t* __restrict__ W1b_p, const float* __restrict__ b1b,
    ushort_t* __restrict__ pooled_bf, float* __restrict__ new_p)
{
    __shared__ __align__(16) ushort_t Wl[49152]; // 96 KB
    const int tid = threadIdx.x;
    const int l = tid & 63;
    const int w = tid >> 6;
    const int q = l >> 5;
    const int r32 = l & 31;

    {
        const short8* s = reinterpret_cast<const short8*>(W1b_p);
        short8* d = reinterpret_cast<short8*>(Wl);
        #pragma unroll
        for (int i = 0; i < 12; ++i) d[i * 512 + tid] = s[i * 512 + tid];
    }
    __syncthreads();

    float bias[12];
    #pragma unroll
    for (int nt = 0; nt < 12; ++nt) bias[nt] = b1b[(nt << 5) + r32];

    for (int c = blockIdx.x; c < NCH1; c += gridDim.x) {
        int trow = c * 256 + w * 32 + r32;
        int tr = trow < T_N ? trow : T_N - 1;

        short8 af[8];
        #pragma unroll
        for (int ks = 0; ks < 8; ++ks)
            af[ks] = *reinterpret_cast<const short8*>(&hbuf[(size_t)tr * 128 + (ks << 4) + (q << 3)]);

        #pragma unroll
        for (int g = 0; g < 3; ++g) {
            f32x16 acc[4] = {};
            #pragma unroll
            for (int ks = 0; ks < 8; ++ks) {
                #pragma unroll
                for (int nt2 = 0; nt2 < 4; ++nt2) {
                    short8 bf = *reinterpret_cast<const short8*>(&Wl[((ks * 12 + (g << 2) + nt2) * 64 + l) * 8]);
                    acc[nt2] = __builtin_amdgcn_mfma_f32_32x32x16_bf16(af[ks], bf, acc[nt2], 0, 0, 0);
                }
            }
            if (g == 1) {
                #pragma unroll
                for (int nt2 = 0; nt2 < 4; ++nt2) {
                    #pragma unroll
                    for (int r = 0; r < 16; ++r) {
                        int rl = (r & 3) + ((r >> 2) << 3) + (q << 2);
                        int trow2 = c * 256 + w * 32 + rl;
                        if (trow2 < T_N)
                            new_p[(size_t)trow2 * 128 + (nt2 << 5) + r32] = acc[nt2][r] + bias[4 + nt2];
                    }
                }
            } else {
                #pragma unroll
                for (int r = 0; r < 16; ++r) {
                    int rl = (r & 3) + ((r >> 2) << 3) + (q << 2);
                    int trow2 = c * 256 + w * 32 + rl;
                    bool v2 = trow2 < T_N;
                    int t2 = v2 ? trow2 : T_N - 1;
                    int2 e2 = ((const int2*)edges)[t2];
                    int seg = (g == 0) ? e2.x : e2.y;
                    ushort_t* pb = pooled_bf + (size_t)seg * 128;
                    #pragma unroll
                    for (int nt2 = 0; nt2 < 4; ++nt2) {
                        float val = acc[nt2][r] + bias[(g << 2) + nt2];
                        float other = __shfl_xor(val, 1, 64);
                        if (v2 && !(r32 & 1)) {
                            unsigned dat = (unsigned)f2bf(val) | ((unsigned)f2bf(other) << 16);
                            uint64_t addr = (uint64_t)(uintptr_t)(pb + (nt2 << 5) + r32);
                            asm volatile("global_atomic_pk_add_bf16 %0, %1, off"
                                         :: "v"(addr), "v"(dat) : "memory");
                        }
                    }
                }
            }
        }
    }
}

// K3 (round 7, proven): pooled_bf/counts -> relu(x@W2a+b2a)@W2b+b2b -> new_obj (f32).
__global__ __launch_bounds__(512, 2) void objects_k32(
    const ushort_t* __restrict__ pooled_bf, const float* __restrict__ counts,
    const ushort_t* __restrict__ W2a_p, const float* __restrict__ b2a,
    const ushort_t* __restrict__ W2b_p, const float* __restrict__ b2b,
    float* __restrict__ outp)
{
    __shared__ __align__(16) ushort_t Wa[16384];
    __shared__ __align__(16) ushort_t Wb[16384];
    __shared__ __align__(16) ushort_t hx[8][4096];
    const int tid = threadIdx.x;
    const int l = tid & 63;
    const int w = tid >> 6;
    const int q = l >> 5;
    const int r32 = l & 31;

    {
        const short8* sa = reinterpret_cast<const short8*>(W2a_p);
        const short8* sb = reinterpret_cast<const short8*>(W2b_p);
        short8* da = reinterpret_cast<short8*>(Wa);
        short8* db = reinterpret_cast<short8*>(Wb);
        #pragma unroll
        for (int i = 0; i < 4; ++i) { da[i * 512 + tid] = sa[i * 512 + tid]; db[i * 512 + tid] = sb[i * 512 + tid]; }
    }
    __syncthreads();

    float ba[4], bb[4];
    #pragma unroll
    for (int nt = 0; nt < 4; ++nt) { ba[nt] = b2a[(nt << 5) + r32]; bb[nt] = b2b[(nt << 5) + r32]; }

    for (int c = blockIdx.x; c < NCH3; c += gridDim.x) {
        int row = c * 256 + w * 32 + r32;
        int rr = row < O_N ? row : O_N - 1;
        float inv = 1.0f / fmaxf(counts[rr], 1.0f);

        short8 af[8];
        #pragma unroll
        for (int ks = 0; ks < 8; ++ks) {
            short8 raw = *reinterpret_cast<const short8*>(&pooled_bf[(size_t)rr * 128 + (ks << 4) + (q << 3)]);
            short8 a;
            #pragma unroll
            for (int j = 0; j < 8; ++j) {
                union { float f; unsigned u; } t;
                t.u = ((unsigned)(unsigned short)raw[j]) << 16;
                a[j] = (short)f2bf(t.f * inv);
            }
            af[ks] = a;
        }

        f32x16 acc[4] = {};
        #pragma unroll
        for (int ks = 0; ks < 8; ++ks) {
            #pragma unroll
            for (int nt = 0; nt < 4; ++nt) {
                short8 bf = *reinterpret_cast<const short8*>(&Wa[(((ks << 2) + nt) * 64 + l) * 8]);
                acc[nt] = __builtin_amdgcn_mfma_f32_32x32x16_bf16(af[ks], bf, acc[nt], 0, 0, 0);
            }
        }

        char* hxw = (char*)&hx[w][0];
        #pragma unroll
        for (int nt = 0; nt < 4; ++nt) {
            #pragma unroll
            for (int r = 0; r < 16; ++r) {
                int rl = (r & 3) + ((r >> 2) << 3) + (q << 2);
                float hv = fmaxf(acc[nt][r] + ba[nt], 0.0f);
                int off = rl * 256 + (((nt << 5) + r32) << 1);
                off ^= (rl & 15) << 4;
                *(ushort_t*)(hxw + off) = f2bf(hv);
            }
        }
        __syncthreads();

        short8 af2[8];
        #pragma unroll
        for (int ks = 0; ks < 8; ++ks) {
            int off = r32 * 256 + (ks << 5) + (q << 4);
            off ^= (r32 & 15) << 4;
            af2[ks] = *reinterpret_cast<const short8*>(hxw + off);
        }

        f32x16 acc2[4] = {};
        #pragma unroll
        for (int ks = 0; ks < 8; ++ks) {
            #pragma unroll
            for (int nt = 0; nt < 4; ++nt) {
                short8 bf = *reinterpret_cast<const short8*>(&Wb[(((ks << 2) + nt) * 64 + l) * 8]);
                acc2[nt] = __builtin_amdgcn_mfma_f32_32x32x16_bf16(af2[ks], bf, acc2[nt], 0, 0, 0);
            }
        }

        #pragma unroll
        for (int nt = 0; nt < 4; ++nt) {
            #pragma unroll
            for (int r = 0; r < 16; ++r) {
                int rl = (r & 3) + ((r >> 2) << 3) + (q << 2);
                int row2 = c * 256 + w * 32 + rl;
                if (row2 < O_N) outp[(size_t)row2 * 128 + (nt << 5) + r32] = acc2[nt][r] + bb[nt];
            }
        }
        __syncthreads();
    }
}

// ---------------- fallback path (round-1, known-good) ----------------
__device__ __forceinline__ void stage_w(const unsigned short* __restrict__ src,
                                        unsigned short* __restrict__ dst, int tid) {
    const short8* s = reinterpret_cast<const short8*>(src);
    short8* d = reinterpret_cast<short8*>(dst);
    d[tid] = s[tid];
    d[tid + 256] = s[tid + 256];
}

__global__ __launch_bounds__(256, 2) void triples_kernel(
    const float* __restrict__ obj_vecs, const float* __restrict__ pred_vecs,
    const int* __restrict__ edges,
    const unsigned short* __restrict__ W1a_p, const float* __restrict__ b1a,
    const unsigned short* __restrict__ W1b_p, const float* __restrict__ b1b,
    float* __restrict__ pooled, float* __restrict__ new_p, float* __restrict__ counts)
{
    __shared__ __align__(16) unsigned short Apack[24576];
    __shared__ __align__(16) unsigned short Wbuf[2][4096];
    __shared__ int sseg[64], oseg[64];
    const int tid = threadIdx.x;
    const int lane = tid & 63;
    const int w = tid >> 6;
    const int t0 = blockIdx.x * 64;
    if (tid < 64) {
        int s = edges[2 * (t0 + tid)];
        int o = edges[2 * (t0 + tid) + 1];
        sseg[tid] = s; oseg[tid] = o;
        atomicAdd(&counts[s], 1.0f);
        atomicAdd(&counts[o], 1.0f);
    }
    __syncthreads();
    for (int it = 0; it < 24; ++it) {
        int idx = it * 256 + tid;
        int r = idx / 96;
        int c = (idx % 96) * 4;
        const float* srcp;
        if (c < 128)      srcp = obj_vecs  + (size_t)sseg[r] * 128 + c;
        else if (c < 256) srcp = pred_vecs + (size_t)(t0 + r) * 128 + (c - 128);
        else              srcp = obj_vecs  + (size_t)oseg[r] * 128 + (c - 256);
        f32x4 v = *reinterpret_cast<const f32x4*>(srcp);
        int off = (((r >> 4) * 12 + (c >> 5)) << 9)
                + (((r & 15) | (((c & 31) >> 3) << 4)) << 3) + (c & 7);
        Apack[off + 0] = f2bf(v[0]); Apack[off + 1] = f2bf(v[1]);
        Apack[off + 2] = f2bf(v[2]); Apack[off + 3] = f2bf(v[3]);
    }
    stage_w(W1a_p, Wbuf[0], tid);
    __syncthreads();
    f32x4 acc[8];
    #pragma unroll
    for (int n = 0; n < 8; ++n) acc[n] = (f32x4){0.f, 0.f, 0.f, 0.f};
    for (int kk = 0; kk < 12; ++kk) {
        if (kk < 11) stage_w(W1a_p + (kk + 1) * 4096, Wbuf[(kk + 1) & 1], tid);
        short8 a = *reinterpret_cast<const short8*>(&Apack[((w * 12 + kk) << 9) + (lane << 3)]);
        const unsigned short* wb = Wbuf[kk & 1];
        #pragma unroll
        for (int n = 0; n < 8; ++n) {
            short8 b = *reinterpret_cast<const short8*>(&wb[((n << 6) + lane) << 3]);
            acc[n] = __builtin_amdgcn_mfma_f32_16x16x32_bf16(a, b, acc[n], 0, 0, 0);
        }
        __syncthreads();
    }
    #pragma unroll
    for (int n = 0; n < 8; ++n) {
        int col = (n << 4) + (lane & 15);
        float bias = b1a[col];
        int base = ((w * 4 + (col >> 5)) << 9) + (col & 7);
        int chi = ((col & 31) >> 3) << 4;
        #pragma unroll
        for (int jj = 0; jj < 4; ++jj) {
            int rloc = ((lane >> 4) << 2) + jj;
            float hv = acc[n][jj] + bias;
            hv = hv > 0.f ? hv : 0.f;
            Apack[base + ((rloc | chi) << 3)] = f2bf(hv);
        }
    }
    for (int g = 0; g < 3; ++g) {
        const unsigned short* Wsrc = W1b_p + g * 16384;
        stage_w(Wsrc, Wbuf[0], tid);
        __syncthreads();
        f32x4 acc2[8];
        #pragma unroll
        for (int n = 0; n < 8; ++n) acc2[n] = (f32x4){0.f, 0.f, 0.f, 0.f};
        for (int kk = 0; kk < 4; ++kk) {
            if (kk < 3) stage_w(Wsrc + (kk + 1) * 4096, Wbuf[(kk + 1) & 1], tid);
            short8 a = *reinterpret_cast<const short8*>(&Apack[((w * 4 + kk) << 9) + (lane << 3)]);
            const unsigned short* wb = Wbuf[kk & 1];
            #pragma unroll
            for (int n = 0; n < 8; ++n) {
                short8 b = *reinterpret_cast<const short8*>(&wb[((n << 6) + lane) << 3]);
                acc2[n] = __builtin_amdgcn_mfma_f32_16x16x32_bf16(a, b, acc2[n], 0, 0, 0);
            }
            __syncthreads();
        }
        #pragma unroll
        for (int n = 0; n < 8; ++n) {
            int col = (n << 4) + (lane & 15);
            float bias = b1b[g * 128 + col];
            #pragma unroll
            for (int jj = 0; jj < 4; ++jj) {
                int rloc = (w << 4) + ((lane >> 4) << 2) + jj;
                float val = acc2[n][jj] + bias;
                if (g == 1) {
                    new_p[(size_t)(t0 + rloc) * 128 + col] = val;
                } else {
                    int seg = (g == 0) ? sseg[rloc] : oseg[rloc];
                    atomicAdd(&pooled[(size_t)seg * 128 + col], val);
                }
            }
        }
    }
}

__global__ __launch_bounds__(256, 2) void objects_kernel(
    const float* __restrict__ counts,
    const unsigned short* __restrict__ W2a_p, const float* __restrict__ b2a,
    const unsigned short* __restrict__ W2b_p, const float* __restrict__ b2b,
    float* __restrict__ inout)
{
    __shared__ __align__(16) unsigned short Apack[8192];
    __shared__ __align__(16) unsigned short Hpack[8192];
    __shared__ __align__(16) unsigned short Wbuf[2][4096];
    const int tid = threadIdx.x;
    const int lane = tid & 63;
    const int w = tid >> 6;
    const int r0 = blockIdx.x * 64;
    for (int it = 0; it < 8; ++it) {
        int idx = it * 256 + tid;
        int r = idx >> 5;
        int c = (idx & 31) << 2;
        int row = r0 + r;
        float vals[4] = {0.f, 0.f, 0.f, 0.f};
        if (row < O_N) {
            f32x4 v = *reinterpret_cast<const f32x4*>(&inout[(size_t)row * 128 + c]);
            float inv = 1.0f / fmaxf(counts[row], 1.0f);
            vals[0] = v[0] * inv; vals[1] = v[1] * inv;
            vals[2] = v[2] * inv; vals[3] = v[3] * inv;
        }
        int off = (((r >> 4) * 4 + (c >> 5)) << 9)
                + (((r & 15) | (((c & 31) >> 3) << 4)) << 3) + (c & 7);
        Apack[off + 0] = f2bf(vals[0]); Apack[off + 1] = f2bf(vals[1]);
        Apack[off + 2] = f2bf(vals[2]); Apack[off + 3] = f2bf(vals[3]);
    }
    stage_w(W2a_p, Wbuf[0], tid);
    __syncthreads();
    f32x4 acc[8];
    #pragma unroll
    for (int n = 0; n < 8; ++n) acc[n] = (f32x4){0.f, 0.f, 0.f, 0.f};
    for (int kk = 0; kk < 4; ++kk) {
        if (kk < 3) stage_w(W2a_p + (kk + 1) * 4096, Wbuf[(kk + 1) & 1], tid);
        short8 a = *reinterpret_cast<const short8*>(&Apack[((w * 4 + kk) << 9) + (lane << 3)]);
        const unsigned short* wb = Wbuf[kk & 1];
        #pragma unroll
        for (int n = 0; n < 8; ++n) {
            short8 b = *reinterpret_cast<const short8*>(&wb[((n << 6) + lane) << 3]);
            acc[n] = __builtin_amdgcn_mfma_f32_16x16x32_bf16(a, b, acc[n], 0, 0, 0);
        }
        __syncthreads();
    }
    #pragma unroll
    for (int n = 0; n < 8; ++n) {
        int col = (n << 4) + (lane & 15);
        float bias = b2a[col];
        int base = ((w * 4 + (col >> 5)) << 9) + (col & 7);
        int chi = ((col & 31) >> 3) << 4;
        #pragma unroll
        for (int jj = 0; jj < 4; ++jj) {
            int rloc = ((lane >> 4) << 2) + jj;
            float hv = acc[n][jj] + bias;
            hv = hv > 0.f ? hv : 0.f;
            Hpack[base + ((rloc | chi) << 3)] = f2bf(hv);
        }
    }
    stage_w(W2b_p, Wbuf[0], tid);
    __syncthreads();
    f32x4 acc2[8];
    #pragma unroll
    for (int n = 0; n < 8; ++n) acc2[n] = (f32x4){0.f, 0.f, 0.f, 0.f};
    for (int kk = 0; kk < 4; ++kk) {
        if (kk < 3) stage_w(W2b_p + (kk + 1) * 4096, Wbuf[(kk + 1) & 1], tid);
        short8 a = *reinterpret_cast<const short8*>(&Hpack[((w * 4 + kk) << 9) + (lane << 3)]);
        const unsigned short* wb = Wbuf[kk & 1];
        #pragma unroll
        for (int n = 0; n < 8; ++n) {
            short8 b = *reinterpret_cast<const short8*>(&wb[((n << 6) + lane) << 3]);
            acc2[n] = __builtin_amdgcn_mfma_f32_16x16x32_bf16(a, b, acc2[n], 0, 0, 0);
        }
        __syncthreads();
    }
    #pragma unroll
    for (int n = 0; n < 8; ++n) {
        int col = (n << 4) + (lane & 15);
        float bias = b2b[col];
        #pragma unroll
        for (int jj = 0; jj < 4; ++jj) {
            int rloc = (w << 4) + ((lane >> 4) << 2) + jj;
            int row = r0 + rloc;
            if (row < O_N) inout[(size_t)row * 128 + col] = acc2[n][jj] + bias;
        }
    }
}

extern "C" void kernel_launch(void* const* d_in, const int* in_sizes, int n_in,
                              void* d_out, int out_size, void* d_ws, size_t ws_size,
                              hipStream_t stream)
{
    const float* obj   = (const float*)d_in[0];
    const float* pred  = (const float*)d_in[1];
    const int*   edges = (const int*)d_in[2];
    const float* W1a = (const float*)d_in[3];
    const float* b1a = (const float*)d_in[4];
    const float* W1b = (const float*)d_in[5];
    const float* b1b = (const float*)d_in[6];
    const float* W2a = (const float*)d_in[7];
    const float* b2a = (const float*)d_in[8];
    const float* W2b = (const float*)d_in[9];
    const float* b2b = (const float*)d_in[10];

    float* out    = (float*)d_out;
    float* new_p  = out + (size_t)O_N * 128;   // T x 128

    uintptr_t wsbase = (uintptr_t)d_ws;
    float* counts = (float*)wsbase;
    uintptr_t p = (wsbase + (size_t)O_N * 4 + 255) & ~(uintptr_t)255;
    ushort_t* pooled_bf = (ushort_t*)p;  p += (size_t)O_N * 128 * 2;    // 25.6 MB
    ushort_t* W1a_p = (ushort_t*)p;  p += (size_t)49152 * 2;            // 16x16 pack (gemm1)
    ushort_t* W1b_p = (ushort_t*)p;  p += (size_t)49152 * 2;            // 32x32 pack (gemm2)
    ushort_t* W2a_p = (ushort_t*)p;  p += (size_t)16384 * 2;
    ushort_t* W2b_p = (ushort_t*)p;  p += (size_t)16384 * 2;
    ushort_t* hbuf  = (ushort_t*)p;  p += (size_t)T_N * 128 * 2;        // 102.4 MB row-major
    size_t need = p - wsbase;

    hipMemsetAsync(counts, 0, (size_t)O_N * sizeof(float), stream);

    if (ws_size >= need) {
        hipMemsetAsync(pooled_bf, 0, (size_t)O_N * 128 * 2, stream);

        pack_all<<<512, 256, 0, stream>>>(W1a, W1b, W2a, W2b, W1a_p, W1b_p, W2a_p, W2b_p);
        counts_k<<<(T_N + 255) / 256, 256, 0, stream>>>(edges, counts);

        gemm1_k<<<256, 1024, 0, stream>>>(obj, pred, edges, W1a_p, b1a, hbuf);
        gemm2_k<<<256, 512, 0, stream>>>(hbuf, edges, W1b_p, b1b, pooled_bf, new_p);
        objects_k32<<<391, 512, 0, stream>>>(pooled_bf, counts, W2a_p, b2a, W2b_p, b2b, out);
    } else {
        // fallback: round-1 fused path (correct, slower); pooled f32 in d_out
        float* pooled = out;
        hipMemsetAsync(pooled, 0, (size_t)O_N * 128 * sizeof(float), stream);

        pack_b<<<192, 256, 0, stream>>>(W1a, W1a_p, 384, 8, 128, 0);
        pack_b<<<64, 256, 0, stream>>>(W1b, W1b_p,         128, 8, 384, 0);
        pack_b<<<64, 256, 0, stream>>>(W1b, W1b_p + 16384, 128, 8, 384, 128);
        pack_b<<<64, 256, 0, stream>>>(W1b, W1b_p + 32768, 128, 8, 384, 256);
        pack_b<<<64, 256, 0, stream>>>(W2a, W2a_p, 128, 8, 128, 0);
        pack_b<<<64, 256, 0, stream>>>(W2b, W2b_p, 128, 8, 128, 0);

        triples_kernel<<<T_N / 64, 256, 0, stream>>>(obj, pred, edges,
                                                     W1a_p, b1a, W1b_p, b1b,
                                                     pooled, new_p, counts);
        objects_kernel<<<(O_N + 63) / 64, 256, 0, stream>>>(counts, W2a_p, b2a, W2b_p, b2b, out);
    }
}